// Round 1
// baseline (381.613 us; speedup 1.0000x reference)
//
#include <hip/hip_runtime.h>
#include <math.h>

#define EPS 1e-8f
#define NSPLIT 16

// ---------------------------------------------------------------------------
// K0: row norms. Blocks [0,S) -> rinv[s] = 1/(||S_s||+eps).
//     Blocks [S, S+B) -> Hs[b,:] = H[b,:]/(||H_b||+eps), gscale[b]=0.005*||G_b||
// ---------------------------------------------------------------------------
__global__ void k_norms(const float* __restrict__ Sg, const float* __restrict__ Hg,
                        const float* __restrict__ Gg, float* __restrict__ rinv,
                        float* __restrict__ Hs, float* __restrict__ gscale,
                        int Srows, int Fdim, int Bdim) {
    __shared__ float wsum[4];
    __shared__ float wsum2[4];
    __shared__ float bc0;
    int row = blockIdx.x;
    int tid = threadIdx.x;
    int lane = tid & 63, wv = tid >> 6;

    if (row < Srows) {
        const float* p = Sg + (size_t)row * Fdim;
        float acc = 0.f;
        for (int i = tid; i < Fdim; i += 256) { float v = p[i]; acc += v * v; }
        for (int off = 32; off > 0; off >>= 1) acc += __shfl_down(acc, off, 64);
        if (lane == 0) wsum[wv] = acc;
        __syncthreads();
        if (tid == 0) {
            float t = wsum[0] + wsum[1] + wsum[2] + wsum[3];
            rinv[row] = 1.0f / (sqrtf(t) + EPS);
        }
    } else {
        int b = row - Srows;
        if (b >= Bdim) return;
        const float* ph = Hg + (size_t)b * Fdim;
        const float* pg = Gg + (size_t)b * Fdim;
        float ah = 0.f, ag = 0.f;
        for (int i = tid; i < Fdim; i += 256) {
            float h = ph[i]; ah += h * h;
            float g = pg[i]; ag += g * g;
        }
        for (int off = 32; off > 0; off >>= 1) {
            ah += __shfl_down(ah, off, 64);
            ag += __shfl_down(ag, off, 64);
        }
        if (lane == 0) { wsum[wv] = ah; wsum2[wv] = ag; }
        __syncthreads();
        if (tid == 0) {
            float th = wsum[0] + wsum[1] + wsum[2] + wsum[3];
            float tg = wsum2[0] + wsum2[1] + wsum2[2] + wsum2[3];
            bc0 = 1.0f / (sqrtf(th) + EPS);
            gscale[b] = 0.005f * sqrtf(tg);
        }
        __syncthreads();
        float hn = bc0;
        float* dst = Hs + (size_t)b * Fdim;
        for (int i = tid; i < Fdim; i += 256) dst[i] = ph[i] * hn;
    }
}

// ---------------------------------------------------------------------------
// K1: edge scatter. W'[s,d] += w*rinv[s];  colsum[d] += w
// ---------------------------------------------------------------------------
__global__ void k_scatter(const float* __restrict__ ew, const int* __restrict__ ed,
                          const int* __restrict__ es, const float* __restrict__ rinv,
                          float* __restrict__ W, float* __restrict__ colsum,
                          int E, int Dd) {
    int e = blockIdx.x * 256 + threadIdx.x;
    if (e >= E) return;
    int s = es[e];
    int d = ed[e];
    float w = ew[e];
    atomicAdd(&W[(size_t)s * Dd + d], w * rinv[s]);
    atomicAdd(&colsum[d], w);
}

// ---------------------------------------------------------------------------
// K2: GEMM1  P[b,s] = Hs[b,:] . S[s,:]   (M=64, N=S, K=F; both row-major on K)
// Tile: 64b x 32s, KT=64. Block 256 threads: tx(16)->s (2 each), ty(16)->b (4 each)
// ---------------------------------------------------------------------------
#define G1_TS 32
#define G1_KT 64
__global__ __launch_bounds__(256) void k_gemm1(
        const float* __restrict__ Hs, const float* __restrict__ Sg,
        float* __restrict__ P, int Srows, int Fdim) {
    __shared__ float lA[64][G1_KT + 1];      // Hs[b][k]
    __shared__ float lB[G1_TS][G1_KT + 1];   // S[s][k]
    int tid = threadIdx.x;
    int tx = tid & 15;   // s group: 2 each
    int ty = tid >> 4;   // b group: 4 each
    int s0 = blockIdx.x * G1_TS;

    float acc[2][4];
    #pragma unroll
    for (int i = 0; i < 2; i++)
        #pragma unroll
        for (int j = 0; j < 4; j++) acc[i][j] = 0.f;

    for (int k0 = 0; k0 < Fdim; k0 += G1_KT) {
        for (int idx = tid; idx < 64 * G1_KT; idx += 256) {
            int r = idx >> 6, c = idx & 63;
            lA[r][c] = Hs[(size_t)r * Fdim + k0 + c];
        }
        for (int idx = tid; idx < G1_TS * G1_KT; idx += 256) {
            int r = idx >> 6, c = idx & 63;
            lB[r][c] = Sg[(size_t)(s0 + r) * Fdim + k0 + c];
        }
        __syncthreads();
        #pragma unroll
        for (int k = 0; k < G1_KT; k++) {
            float a0 = lA[ty * 4 + 0][k];
            float a1 = lA[ty * 4 + 1][k];
            float a2 = lA[ty * 4 + 2][k];
            float a3 = lA[ty * 4 + 3][k];
            float b0 = lB[tx * 2 + 0][k];
            float b1 = lB[tx * 2 + 1][k];
            acc[0][0] += b0 * a0; acc[0][1] += b0 * a1;
            acc[0][2] += b0 * a2; acc[0][3] += b0 * a3;
            acc[1][0] += b1 * a0; acc[1][1] += b1 * a1;
            acc[1][2] += b1 * a2; acc[1][3] += b1 * a3;
        }
        __syncthreads();
    }
    #pragma unroll
    for (int j = 0; j < 4; j++) {
        int b = ty * 4 + j;
        #pragma unroll
        for (int i = 0; i < 2; i++) {
            int s = s0 + tx * 2 + i;
            P[(size_t)b * Srows + s] = acc[i][j];
        }
    }
}

// ---------------------------------------------------------------------------
// K3: GEMM2  part[kc][b][d] = sum_{k in chunk} P[b,k] * W[k,d]
// M=64(b), N=D(d), K=S. Split-K: NSPLIT chunks. Tile 64b x 64d, KT=32.
// tx(16)->d (4 each), ty(16)->b (4 each).
// ---------------------------------------------------------------------------
#define G2_TD 64
#define G2_KT 32
__global__ __launch_bounds__(256) void k_gemm2(
        const float* __restrict__ P, const float* __restrict__ W,
        float* __restrict__ part, int Srows, int Dd, int Bdim) {
    __shared__ float lA[64][G2_KT + 1];   // P[b][k]
    __shared__ float lB[G2_KT][G2_TD];    // W[k][d]
    int tid = threadIdx.x;
    int tx = tid & 15;   // d group
    int ty = tid >> 4;   // b group
    int d0 = blockIdx.x * G2_TD;
    int kc = blockIdx.y;
    int kchunk = Srows / NSPLIT;
    int kbase = kc * kchunk;

    float acc[4][4];
    #pragma unroll
    for (int i = 0; i < 4; i++)
        #pragma unroll
        for (int j = 0; j < 4; j++) acc[i][j] = 0.f;

    for (int kt = 0; kt < kchunk; kt += G2_KT) {
        for (int idx = tid; idx < 64 * G2_KT; idx += 256) {
            int r = idx >> 5, c = idx & 31;
            lA[r][c] = P[(size_t)r * Srows + kbase + kt + c];
        }
        for (int idx = tid; idx < G2_KT * G2_TD; idx += 256) {
            int r = idx >> 6, c = idx & 63;
            lB[r][c] = W[(size_t)(kbase + kt + r) * Dd + d0 + c];
        }
        __syncthreads();
        #pragma unroll
        for (int k = 0; k < G2_KT; k++) {
            float a0 = lA[ty * 4 + 0][k];
            float a1 = lA[ty * 4 + 1][k];
            float a2 = lA[ty * 4 + 2][k];
            float a3 = lA[ty * 4 + 3][k];
            float b0 = lB[k][tx * 4 + 0];
            float b1 = lB[k][tx * 4 + 1];
            float b2 = lB[k][tx * 4 + 2];
            float b3 = lB[k][tx * 4 + 3];
            acc[0][0] += a0 * b0; acc[0][1] += a0 * b1; acc[0][2] += a0 * b2; acc[0][3] += a0 * b3;
            acc[1][0] += a1 * b0; acc[1][1] += a1 * b1; acc[1][2] += a1 * b2; acc[1][3] += a1 * b3;
            acc[2][0] += a2 * b0; acc[2][1] += a2 * b1; acc[2][2] += a2 * b2; acc[2][3] += a2 * b3;
            acc[3][0] += a3 * b0; acc[3][1] += a3 * b1; acc[3][2] += a3 * b2; acc[3][3] += a3 * b3;
        }
        __syncthreads();
    }
    #pragma unroll
    for (int i = 0; i < 4; i++) {
        int b = ty * 4 + i;
        #pragma unroll
        for (int j = 0; j < 4; j++) {
            int d = d0 + tx * 4 + j;
            part[((size_t)kc * Bdim + b) * Dd + d] = acc[i][j];
        }
    }
}

// ---------------------------------------------------------------------------
// K4: epilogue  out[b,d] = gscale[b] * (sum_kc part[kc][b][d] + colsum[d])
// ---------------------------------------------------------------------------
__global__ void k_epi(const float* __restrict__ part, const float* __restrict__ colsum,
                      const float* __restrict__ gscale, float* __restrict__ out,
                      int Dd, int Bdim) {
    int idx = blockIdx.x * 256 + threadIdx.x;
    if (idx >= Bdim * Dd) return;
    int b = idx / Dd;
    int d = idx - b * Dd;
    float s = 0.f;
    #pragma unroll
    for (int kc = 0; kc < NSPLIT; kc++)
        s += part[((size_t)kc * Bdim + b) * Dd + d];
    out[idx] = gscale[b] * (s + colsum[d]);
}

extern "C" void kernel_launch(void* const* d_in, const int* in_sizes, int n_in,
                              void* d_out, int out_size, void* d_ws, size_t ws_size,
                              hipStream_t stream) {
    const float* H  = (const float*)d_in[0];
    const float* G  = (const float*)d_in[1];
    const float* Sg = (const float*)d_in[2];
    const float* ew = (const float*)d_in[3];
    const int*   ed = (const int*)d_in[4];
    const int*   es = (const int*)d_in[5];

    const int B = 64;
    const int F = in_sizes[0] / B;        // 512
    const int S = in_sizes[2] / F;        // 8192
    const int E = in_sizes[3];            // 500000
    const int D = out_size / B;           // 1024
    float* out = (float*)d_out;

    // workspace layout (floats)
    float* ws = (float*)d_ws;
    size_t off = 0;
    float* rinv   = ws + off; off += (size_t)S;            // 8192
    float* Hs     = ws + off; off += (size_t)B * F;        // 32768
    float* gscale = ws + off; off += 256;                  // 64 used, padded
    float* colsum = ws + off; off += (size_t)D;            // 1024 (adjacent to W)
    float* W      = ws + off; off += (size_t)S * D;        // 8.4M
    float* P      = ws + off; off += (size_t)B * S;        // 524288
    float* part   = ws + off; off += (size_t)NSPLIT * B * D; // 1M

    // zero colsum + W in one shot (adjacent)
    hipMemsetAsync(colsum, 0, ((size_t)S * D + D) * sizeof(float), stream);

    k_norms<<<S + B, 256, 0, stream>>>(Sg, H, G, rinv, Hs, gscale, S, F, B);
    k_scatter<<<(E + 255) / 256, 256, 0, stream>>>(ew, ed, es, rinv, W, colsum, E, D);
    k_gemm1<<<S / G1_TS, 256, 0, stream>>>(Hs, Sg, P, S, F);
    dim3 g2(D / G2_TD, NSPLIT);
    k_gemm2<<<g2, 256, 0, stream>>>(P, W, part, S, D, B);
    k_epi<<<(B * D + 255) / 256, 256, 0, stream>>>(part, colsum, gscale, out, D, B);
}

// Round 2
// 280.041 us; speedup vs baseline: 1.3627x; 1.3627x over previous
//
#include <hip/hip_runtime.h>
#include <math.h>

#define EPS 1e-8f
#define NSPLIT 16
#define SCAT_BLOCKS 512

// ---------------------------------------------------------------------------
// K0: row norms. Blocks [0,S) -> rinv[s] = 1/(||S_s||+eps).
//     Blocks [S, S+B) -> Hs[b,:] = H[b,:]/(||H_b||+eps), gscale[b]=0.005*||G_b||
// ---------------------------------------------------------------------------
__global__ void k_norms(const float* __restrict__ Sg, const float* __restrict__ Hg,
                        const float* __restrict__ Gg, float* __restrict__ rinv,
                        float* __restrict__ Hs, float* __restrict__ gscale,
                        int Srows, int Fdim, int Bdim) {
    __shared__ float wsum[4];
    __shared__ float wsum2[4];
    __shared__ float bc0;
    int row = blockIdx.x;
    int tid = threadIdx.x;
    int lane = tid & 63, wv = tid >> 6;

    if (row < Srows) {
        const float* p = Sg + (size_t)row * Fdim;
        float acc = 0.f;
        for (int i = tid; i < Fdim; i += 256) { float v = p[i]; acc += v * v; }
        for (int off = 32; off > 0; off >>= 1) acc += __shfl_down(acc, off, 64);
        if (lane == 0) wsum[wv] = acc;
        __syncthreads();
        if (tid == 0) {
            float t = wsum[0] + wsum[1] + wsum[2] + wsum[3];
            rinv[row] = 1.0f / (sqrtf(t) + EPS);
        }
    } else {
        int b = row - Srows;
        if (b >= Bdim) return;
        const float* ph = Hg + (size_t)b * Fdim;
        const float* pg = Gg + (size_t)b * Fdim;
        float ah = 0.f, ag = 0.f;
        for (int i = tid; i < Fdim; i += 256) {
            float h = ph[i]; ah += h * h;
            float g = pg[i]; ag += g * g;
        }
        for (int off = 32; off > 0; off >>= 1) {
            ah += __shfl_down(ah, off, 64);
            ag += __shfl_down(ag, off, 64);
        }
        if (lane == 0) { wsum[wv] = ah; wsum2[wv] = ag; }
        __syncthreads();
        if (tid == 0) {
            float th = wsum[0] + wsum[1] + wsum[2] + wsum[3];
            float tg = wsum2[0] + wsum2[1] + wsum2[2] + wsum2[3];
            bc0 = 1.0f / (sqrtf(th) + EPS);
            gscale[b] = 0.005f * sqrtf(tg);
        }
        __syncthreads();
        float hn = bc0;
        float* dst = Hs + (size_t)b * Fdim;
        for (int i = tid; i < Fdim; i += 256) dst[i] = ph[i] * hn;
    }
}

// ---------------------------------------------------------------------------
// K1: edge scatter. W'[s,d] += w*rinv[s]  (global atomics, spread addresses)
//     colsum partials via per-block LDS histogram -> pcs[block][D]
// ---------------------------------------------------------------------------
__global__ __launch_bounds__(256) void k_scatter(
        const float* __restrict__ ew, const int* __restrict__ ed,
        const int* __restrict__ es, const float* __restrict__ rinv,
        float* __restrict__ W, float* __restrict__ pcs,
        int E, int Dd) {
    __shared__ float bins[1024];
    int tid = threadIdx.x;
    for (int i = tid; i < Dd; i += 256) bins[i] = 0.f;
    __syncthreads();

    int stride = gridDim.x * 256;
    for (int e = blockIdx.x * 256 + tid; e < E; e += stride) {
        int s = es[e];
        int d = ed[e];
        float w = ew[e];
        atomicAdd(&W[(size_t)s * Dd + d], w * rinv[s]);
        atomicAdd(&bins[d], w);
    }
    __syncthreads();
    float* dst = pcs + (size_t)blockIdx.x * Dd;
    for (int i = tid; i < Dd; i += 256) dst[i] = bins[i];
}

// reduce pcs[SCAT_BLOCKS][D] -> colsum[D]
__global__ void k_colsum_reduce(const float* __restrict__ pcs,
                                float* __restrict__ colsum, int Dd) {
    int d = blockIdx.x * 256 + threadIdx.x;
    if (d >= Dd) return;
    float s = 0.f;
    for (int blk = 0; blk < SCAT_BLOCKS; blk++)
        s += pcs[(size_t)blk * Dd + d];
    colsum[d] = s;
}

// ---------------------------------------------------------------------------
// K2: GEMM1  P[b,s] = Hs[b,:] . S[s,:]   (M=64, N=S, K=F; both row-major on K)
// ---------------------------------------------------------------------------
#define G1_TS 32
#define G1_KT 64
__global__ __launch_bounds__(256) void k_gemm1(
        const float* __restrict__ Hs, const float* __restrict__ Sg,
        float* __restrict__ P, int Srows, int Fdim) {
    __shared__ float lA[64][G1_KT + 1];      // Hs[b][k]
    __shared__ float lB[G1_TS][G1_KT + 1];   // S[s][k]
    int tid = threadIdx.x;
    int tx = tid & 15;   // s group: 2 each
    int ty = tid >> 4;   // b group: 4 each
    int s0 = blockIdx.x * G1_TS;

    float acc[2][4];
    #pragma unroll
    for (int i = 0; i < 2; i++)
        #pragma unroll
        for (int j = 0; j < 4; j++) acc[i][j] = 0.f;

    for (int k0 = 0; k0 < Fdim; k0 += G1_KT) {
        for (int idx = tid; idx < 64 * G1_KT; idx += 256) {
            int r = idx >> 6, c = idx & 63;
            lA[r][c] = Hs[(size_t)r * Fdim + k0 + c];
        }
        for (int idx = tid; idx < G1_TS * G1_KT; idx += 256) {
            int r = idx >> 6, c = idx & 63;
            lB[r][c] = Sg[(size_t)(s0 + r) * Fdim + k0 + c];
        }
        __syncthreads();
        #pragma unroll
        for (int k = 0; k < G1_KT; k++) {
            float a0 = lA[ty * 4 + 0][k];
            float a1 = lA[ty * 4 + 1][k];
            float a2 = lA[ty * 4 + 2][k];
            float a3 = lA[ty * 4 + 3][k];
            float b0 = lB[tx * 2 + 0][k];
            float b1 = lB[tx * 2 + 1][k];
            acc[0][0] += b0 * a0; acc[0][1] += b0 * a1;
            acc[0][2] += b0 * a2; acc[0][3] += b0 * a3;
            acc[1][0] += b1 * a0; acc[1][1] += b1 * a1;
            acc[1][2] += b1 * a2; acc[1][3] += b1 * a3;
        }
        __syncthreads();
    }
    #pragma unroll
    for (int j = 0; j < 4; j++) {
        int b = ty * 4 + j;
        #pragma unroll
        for (int i = 0; i < 2; i++) {
            int s = s0 + tx * 2 + i;
            P[(size_t)b * Srows + s] = acc[i][j];
        }
    }
}

// ---------------------------------------------------------------------------
// K3: GEMM2  part[kc][b][d] = sum_{k in chunk} P[b,k] * W[k,d]
// ---------------------------------------------------------------------------
#define G2_TD 64
#define G2_KT 32
__global__ __launch_bounds__(256) void k_gemm2(
        const float* __restrict__ P, const float* __restrict__ W,
        float* __restrict__ part, int Srows, int Dd, int Bdim) {
    __shared__ float lA[64][G2_KT + 1];   // P[b][k]
    __shared__ float lB[G2_KT][G2_TD];    // W[k][d]
    int tid = threadIdx.x;
    int tx = tid & 15;   // d group
    int ty = tid >> 4;   // b group
    int d0 = blockIdx.x * G2_TD;
    int kc = blockIdx.y;
    int kchunk = Srows / NSPLIT;
    int kbase = kc * kchunk;

    float acc[4][4];
    #pragma unroll
    for (int i = 0; i < 4; i++)
        #pragma unroll
        for (int j = 0; j < 4; j++) acc[i][j] = 0.f;

    for (int kt = 0; kt < kchunk; kt += G2_KT) {
        for (int idx = tid; idx < 64 * G2_KT; idx += 256) {
            int r = idx >> 5, c = idx & 31;
            lA[r][c] = P[(size_t)r * Srows + kbase + kt + c];
        }
        for (int idx = tid; idx < G2_KT * G2_TD; idx += 256) {
            int r = idx >> 6, c = idx & 63;
            lB[r][c] = W[(size_t)(kbase + kt + r) * Dd + d0 + c];
        }
        __syncthreads();
        #pragma unroll
        for (int k = 0; k < G2_KT; k++) {
            float a0 = lA[ty * 4 + 0][k];
            float a1 = lA[ty * 4 + 1][k];
            float a2 = lA[ty * 4 + 2][k];
            float a3 = lA[ty * 4 + 3][k];
            float b0 = lB[k][tx * 4 + 0];
            float b1 = lB[k][tx * 4 + 1];
            float b2 = lB[k][tx * 4 + 2];
            float b3 = lB[k][tx * 4 + 3];
            acc[0][0] += a0 * b0; acc[0][1] += a0 * b1; acc[0][2] += a0 * b2; acc[0][3] += a0 * b3;
            acc[1][0] += a1 * b0; acc[1][1] += a1 * b1; acc[1][2] += a1 * b2; acc[1][3] += a1 * b3;
            acc[2][0] += a2 * b0; acc[2][1] += a2 * b1; acc[2][2] += a2 * b2; acc[2][3] += a2 * b3;
            acc[3][0] += a3 * b0; acc[3][1] += a3 * b1; acc[3][2] += a3 * b2; acc[3][3] += a3 * b3;
        }
        __syncthreads();
    }
    #pragma unroll
    for (int i = 0; i < 4; i++) {
        int b = ty * 4 + i;
        #pragma unroll
        for (int j = 0; j < 4; j++) {
            int d = d0 + tx * 4 + j;
            part[((size_t)kc * Bdim + b) * Dd + d] = acc[i][j];
        }
    }
}

// ---------------------------------------------------------------------------
// K4: epilogue  out[b,d] = gscale[b] * (sum_kc part[kc][b][d] + colsum[d])
// ---------------------------------------------------------------------------
__global__ void k_epi(const float* __restrict__ part, const float* __restrict__ colsum,
                      const float* __restrict__ gscale, float* __restrict__ out,
                      int Dd, int Bdim) {
    int idx = blockIdx.x * 256 + threadIdx.x;
    if (idx >= Bdim * Dd) return;
    int b = idx / Dd;
    int d = idx - b * Dd;
    float s = 0.f;
    #pragma unroll
    for (int kc = 0; kc < NSPLIT; kc++)
        s += part[((size_t)kc * Bdim + b) * Dd + d];
    out[idx] = gscale[b] * (s + colsum[d]);
}

extern "C" void kernel_launch(void* const* d_in, const int* in_sizes, int n_in,
                              void* d_out, int out_size, void* d_ws, size_t ws_size,
                              hipStream_t stream) {
    const float* H  = (const float*)d_in[0];
    const float* G  = (const float*)d_in[1];
    const float* Sg = (const float*)d_in[2];
    const float* ew = (const float*)d_in[3];
    const int*   ed = (const int*)d_in[4];
    const int*   es = (const int*)d_in[5];

    const int B = 64;
    const int F = in_sizes[0] / B;        // 512
    const int S = in_sizes[2] / F;        // 8192
    const int E = in_sizes[3];            // 500000
    const int D = out_size / B;           // 1024
    float* out = (float*)d_out;

    // workspace layout (floats)
    float* ws = (float*)d_ws;
    size_t off = 0;
    float* rinv   = ws + off; off += (size_t)S;              // 8192
    float* Hs     = ws + off; off += (size_t)B * F;          // 32768
    float* gscale = ws + off; off += 256;                    // 64 used, padded
    float* colsum = ws + off; off += (size_t)D;              // 1024
    float* W      = ws + off; off += (size_t)S * D;          // 8.4M
    float* P      = ws + off; off += (size_t)B * S;          // 524288
    float* part   = ws + off; off += (size_t)NSPLIT * B * D; // 1M
    float* pcs    = ws + off; off += (size_t)SCAT_BLOCKS * D;// 524288

    // zero W only (colsum written by reduce; pcs fully written by scatter)
    hipMemsetAsync(W, 0, (size_t)S * D * sizeof(float), stream);

    k_norms<<<S + B, 256, 0, stream>>>(Sg, H, G, rinv, Hs, gscale, S, F, B);
    k_scatter<<<SCAT_BLOCKS, 256, 0, stream>>>(ew, ed, es, rinv, W, pcs, E, D);
    k_colsum_reduce<<<(D + 255) / 256, 256, 0, stream>>>(pcs, colsum, D);
    k_gemm1<<<S / G1_TS, 256, 0, stream>>>(Hs, Sg, P, S, F);
    dim3 g2(D / G2_TD, NSPLIT);
    k_gemm2<<<g2, 256, 0, stream>>>(P, W, part, S, D, B);
    k_epi<<<(B * D + 255) / 256, 256, 0, stream>>>(part, colsum, gscale, out, D, B);
}

// Round 3
// 191.976 us; speedup vs baseline: 1.9878x; 1.4587x over previous
//
#include <hip/hip_runtime.h>
#include <math.h>

#define EPS 1e-8f
#define SCAT_BLOCKS 512
#define KT 32
#define KC1 2

// ---------------------------------------------------------------------------
// K0: row norms. Blocks [0,S) -> rinv[s] = 1/(||S_s||+eps).
//     Blocks [S, S+B) -> Hs[b,:] = H[b,:]/(||H_b||+eps), gscale[b]=0.005*||G_b||
// ---------------------------------------------------------------------------
__global__ void k_norms(const float* __restrict__ Sg, const float* __restrict__ Hg,
                        const float* __restrict__ Gg, float* __restrict__ rinv,
                        float* __restrict__ Hs, float* __restrict__ gscale,
                        int Srows, int Fdim, int Bdim) {
    __shared__ float wsum[4];
    __shared__ float wsum2[4];
    __shared__ float bc0;
    int row = blockIdx.x;
    int tid = threadIdx.x;
    int lane = tid & 63, wv = tid >> 6;

    if (row < Srows) {
        const float* p = Sg + (size_t)row * Fdim;
        float acc = 0.f;
        for (int i = tid; i < Fdim; i += 256) { float v = p[i]; acc += v * v; }
        for (int off = 32; off > 0; off >>= 1) acc += __shfl_down(acc, off, 64);
        if (lane == 0) wsum[wv] = acc;
        __syncthreads();
        if (tid == 0) {
            float t = wsum[0] + wsum[1] + wsum[2] + wsum[3];
            rinv[row] = 1.0f / (sqrtf(t) + EPS);
        }
    } else {
        int b = row - Srows;
        if (b >= Bdim) return;
        const float* ph = Hg + (size_t)b * Fdim;
        const float* pg = Gg + (size_t)b * Fdim;
        float ah = 0.f, ag = 0.f;
        for (int i = tid; i < Fdim; i += 256) {
            float h = ph[i]; ah += h * h;
            float g = pg[i]; ag += g * g;
        }
        for (int off = 32; off > 0; off >>= 1) {
            ah += __shfl_down(ah, off, 64);
            ag += __shfl_down(ag, off, 64);
        }
        if (lane == 0) { wsum[wv] = ah; wsum2[wv] = ag; }
        __syncthreads();
        if (tid == 0) {
            float th = wsum[0] + wsum[1] + wsum[2] + wsum[3];
            float tg = wsum2[0] + wsum2[1] + wsum2[2] + wsum2[3];
            bc0 = 1.0f / (sqrtf(th) + EPS);
            gscale[b] = 0.005f * sqrtf(tg);
        }
        __syncthreads();
        float hn = bc0;
        float* dst = Hs + (size_t)b * Fdim;
        for (int i = tid; i < Fdim; i += 256) dst[i] = ph[i] * hn;
    }
}

// ---------------------------------------------------------------------------
// K1: edge scatter. W'[s,d] += w*rinv[s]  (global atomics, spread addresses)
//     colsum partials via per-block LDS histogram -> pcs[block][D]
// ---------------------------------------------------------------------------
__global__ __launch_bounds__(256) void k_scatter(
        const float* __restrict__ ew, const int* __restrict__ ed,
        const int* __restrict__ es, const float* __restrict__ rinv,
        float* __restrict__ W, float* __restrict__ pcs,
        int E, int Dd) {
    __shared__ float bins[1024];
    int tid = threadIdx.x;
    for (int i = tid; i < Dd; i += 256) bins[i] = 0.f;
    __syncthreads();

    int stride = gridDim.x * 256;
    for (int e = blockIdx.x * 256 + tid; e < E; e += stride) {
        int s = es[e];
        int d = ed[e];
        float w = ew[e];
        atomicAdd(&W[(size_t)s * Dd + d], w * rinv[s]);
        atomicAdd(&bins[d], w);
    }
    __syncthreads();
    float* dst = pcs + (size_t)blockIdx.x * Dd;
    for (int i = tid; i < Dd; i += 256) dst[i] = bins[i];
}

// reduce pcs[SCAT_BLOCKS][D] -> colsum[D]
__global__ void k_colsum_reduce(const float* __restrict__ pcs,
                                float* __restrict__ colsum, int Dd) {
    int d = blockIdx.x * 256 + threadIdx.x;
    if (d >= Dd) return;
    float s = 0.f;
    for (int blk = 0; blk < SCAT_BLOCKS; blk++)
        s += pcs[(size_t)blk * Dd + d];
    colsum[d] = s;
}

// ---------------------------------------------------------------------------
// K2: GEMM1  part1[kc][b][s] = sum_{k in chunk kc} Hs[b,k] * Sg[s,k]
// Tile 64b x 32s, KT=32, split-K KC1=2. Grid (S/32, KC1) = 512 blocks.
// k-major LDS, float4/float2 fragment reads.
// ---------------------------------------------------------------------------
__global__ __launch_bounds__(256) void k_gemm1(
        const float* __restrict__ Hs, const float* __restrict__ Sg,
        float* __restrict__ part1, int Srows, int Fdim, int kchunk) {
    __shared__ float lA[KT][68];   // [k][b]  (68: 16B-aligned rows, pad)
    __shared__ float lB[KT][68];   // [k][s]
    int tid = threadIdx.x;
    int tx = tid & 15;          // s: 2 each
    int ty = tid >> 4;          // b: 4 each
    int s0 = blockIdx.x * 32;
    int kb = blockIdx.y * kchunk;

    float acc[4][2];
    #pragma unroll
    for (int j = 0; j < 4; j++) { acc[j][0] = 0.f; acc[j][1] = 0.f; }

    for (int kt = 0; kt < kchunk; kt += KT) {
        #pragma unroll
        for (int i = 0; i < 8; i++) {           // 64b x 32k = 2048
            int idx = tid + i * 256;
            int c = idx & 31, r = idx >> 5;
            lA[c][r] = Hs[(size_t)r * Fdim + kb + kt + c];
        }
        #pragma unroll
        for (int i = 0; i < 4; i++) {           // 32s x 32k = 1024
            int idx = tid + i * 256;
            int c = idx & 31, r = idx >> 5;
            lB[c][r] = Sg[(size_t)(s0 + r) * Fdim + kb + kt + c];
        }
        __syncthreads();
        #pragma unroll
        for (int k = 0; k < KT; k++) {
            float4 av = *(const float4*)&lA[k][ty * 4];
            float2 bv = *(const float2*)&lB[k][tx * 2];
            acc[0][0] += av.x * bv.x; acc[0][1] += av.x * bv.y;
            acc[1][0] += av.y * bv.x; acc[1][1] += av.y * bv.y;
            acc[2][0] += av.z * bv.x; acc[2][1] += av.z * bv.y;
            acc[3][0] += av.w * bv.x; acc[3][1] += av.w * bv.y;
        }
        __syncthreads();
    }
    #pragma unroll
    for (int j = 0; j < 4; j++) {
        int b = ty * 4 + j;
        float2 v; v.x = acc[j][0]; v.y = acc[j][1];
        *(float2*)&part1[((size_t)blockIdx.y * 64 + b) * Srows + s0 + tx * 2] = v;
    }
}

// ---------------------------------------------------------------------------
// K3: GEMM2  part[kc][b][d] = sum_{k in chunk} P[b,k] * W[k,d]
// P reconstructed on the fly as sum of KC1 part1 slices during A-staging.
// Tile 64b x 64d, KT=32. Grid (D/64, nsplit). nsplit runtime (ws-dependent).
// ---------------------------------------------------------------------------
__global__ __launch_bounds__(256) void k_gemm2(
        const float* __restrict__ part1, const float* __restrict__ W,
        float* __restrict__ part, int Srows, int Dd, int nsplit) {
    __shared__ float lA[KT][68];    // [k][b]
    __shared__ float lB[KT][64];    // [k][d]
    int tid = threadIdx.x;
    int tx = tid & 15;   // d: 4 each
    int ty = tid >> 4;   // b: 4 each
    int d0 = blockIdx.x * 64;
    int kchunk = Srows / nsplit;
    int kb = blockIdx.y * kchunk;

    float4 acc[4];
    #pragma unroll
    for (int j = 0; j < 4; j++) { acc[j].x = acc[j].y = acc[j].z = acc[j].w = 0.f; }

    for (int kt = 0; kt < kchunk; kt += KT) {
        #pragma unroll
        for (int i = 0; i < 8; i++) {           // 64b x 32k
            int idx = tid + i * 256;
            int c = idx & 31, r = idx >> 5;
            size_t col = (size_t)kb + kt + c;
            float v = part1[(size_t)r * Srows + col]
                    + part1[(size_t)(64 + r) * Srows + col];   // KC1 = 2
            lA[c][r] = v;
        }
        #pragma unroll
        for (int i = 0; i < 8; i++) {           // 32k x 64d
            int idx = tid + i * 256;
            int c = idx & 63, r = idx >> 6;
            lB[r][c] = W[(size_t)(kb + kt + r) * Dd + d0 + c];
        }
        __syncthreads();
        #pragma unroll
        for (int k = 0; k < KT; k++) {
            float4 av = *(const float4*)&lA[k][ty * 4];
            float4 bv = *(const float4*)&lB[k][tx * 4];
            acc[0].x += av.x * bv.x; acc[0].y += av.x * bv.y; acc[0].z += av.x * bv.z; acc[0].w += av.x * bv.w;
            acc[1].x += av.y * bv.x; acc[1].y += av.y * bv.y; acc[1].z += av.y * bv.z; acc[1].w += av.y * bv.w;
            acc[2].x += av.z * bv.x; acc[2].y += av.z * bv.y; acc[2].z += av.z * bv.z; acc[2].w += av.z * bv.w;
            acc[3].x += av.w * bv.x; acc[3].y += av.w * bv.y; acc[3].z += av.w * bv.z; acc[3].w += av.w * bv.w;
        }
        __syncthreads();
    }
    #pragma unroll
    for (int j = 0; j < 4; j++) {
        int b = ty * 4 + j;
        *(float4*)&part[((size_t)blockIdx.y * 64 + b) * Dd + d0 + tx * 4] = acc[j];
    }
}

// ---------------------------------------------------------------------------
// K4: epilogue  out[b,d] = gscale[b] * (sum_kc part[kc][b][d] + colsum[d])
// ---------------------------------------------------------------------------
__global__ void k_epi(const float* __restrict__ part, const float* __restrict__ colsum,
                      const float* __restrict__ gscale, float* __restrict__ out,
                      int Dd, int Bdim, int nsplit) {
    int idx = blockIdx.x * 256 + threadIdx.x;
    if (idx >= Bdim * Dd) return;
    int b = idx / Dd;
    int d = idx - b * Dd;
    float s = 0.f;
    for (int kc = 0; kc < nsplit; kc++)
        s += part[((size_t)kc * Bdim + b) * Dd + d];
    out[idx] = gscale[b] * (s + colsum[d]);
}

extern "C" void kernel_launch(void* const* d_in, const int* in_sizes, int n_in,
                              void* d_out, int out_size, void* d_ws, size_t ws_size,
                              hipStream_t stream) {
    const float* H  = (const float*)d_in[0];
    const float* G  = (const float*)d_in[1];
    const float* Sg = (const float*)d_in[2];
    const float* ew = (const float*)d_in[3];
    const int*   ed = (const int*)d_in[4];
    const int*   es = (const int*)d_in[5];

    const int B = 64;
    const int F = in_sizes[0] / B;        // 512
    const int S = in_sizes[2] / F;        // 8192
    const int E = in_sizes[3];            // 500000
    const int D = out_size / B;           // 1024
    float* out = (float*)d_out;

    // workspace layout (floats)
    float* ws = (float*)d_ws;
    size_t off = 0;
    float* rinv   = ws + off; off += (size_t)S;              // 8192
    float* Hs     = ws + off; off += (size_t)B * F;          // 32768
    float* gscale = ws + off; off += 256;                    // pad
    float* colsum = ws + off; off += (size_t)D;              // 1024
    float* W      = ws + off; off += (size_t)S * D;          // 8.39M
    float* part1  = ws + off; off += (size_t)KC1 * B * S;    // 1.05M
    // union region: pcs (scatter phase, dead after colsum_reduce) / part (gemm2 phase)
    float* pcs    = ws + off;
    float* part   = ws + off;

    // split-K factor for gemm2, capped by available scratch
    int ns = 64;
    while (ns > 8) {
        size_t need = off + (size_t)ns * B * D;
        size_t pcs_need = off + (size_t)SCAT_BLOCKS * D;
        if (pcs_need > need) need = pcs_need;
        if (need * sizeof(float) <= ws_size) break;
        ns >>= 1;
    }

    hipMemsetAsync(W, 0, (size_t)S * D * sizeof(float), stream);

    k_norms<<<S + B, 256, 0, stream>>>(Sg, H, G, rinv, Hs, gscale, S, F, B);
    k_scatter<<<SCAT_BLOCKS, 256, 0, stream>>>(ew, ed, es, rinv, W, pcs, E, D);
    k_colsum_reduce<<<(D + 255) / 256, 256, 0, stream>>>(pcs, colsum, D);
    dim3 g1(S / 32, KC1);
    k_gemm1<<<g1, 256, 0, stream>>>(Hs, Sg, part1, S, F, F / KC1);
    dim3 g2(D / 64, ns);
    k_gemm2<<<g2, 256, 0, stream>>>(part1, W, part, S, D, ns);
    k_epi<<<(B * D + 255) / 256, 256, 0, stream>>>(part, colsum, gscale, out, D, B, ns);
}